// Round 1
// 1600.970 us; speedup vs baseline: 1.1010x; 1.1010x over previous
//
#include <hip/hip_runtime.h>

// Problem constants
#define BATCH   64
#define CHAN    384
#define HW      1024
#define SM_PB   (HW * HW)          // score elements per batch = 1048576
#define OUT_OFF 576                // action floats before score matrix
#define KTOP    1024
#define NBUCKET 4096
#define CAND_CAP 8192
#define K2      1536               // expanded K: 4 f16 slots per channel

// Workspace byte offsets
#define WS_INV_CUR   0                      // 64*1024*4 = 262144
#define WS_INV_GOAL  262144                 // 262144
#define WS_HIST      524288                 // 64*4096*4 = 1048576
#define WS_CNT       1572864                // 64*4 (padded to 256)
#define WS_TBUF      1573120                // 64*4 (padded to 256)
#define WS_CAND      1573376                // 64*8192*8 = 4194304
#define WS_FEATS     5767680                // 64*3072*4 = 786432
#define WS_H1        6554112                // 64*1024*4 = 262144
#define WS_H2        6816256                // 64*256*4  = 65536
#define WS_EXP       6881792                // expanded f16 buffers start here
#define EXP_PB       6291456ULL             // bytes per batch: 2 ops * 1024 * 1536 * 2B

using f16x8 = __attribute__((ext_vector_type(8))) _Float16;
using f32x4 = __attribute__((ext_vector_type(4))) float;

__device__ __forceinline__ unsigned mono_key(float f) {
    unsigned u = __float_as_uint(f);
    return u ^ ((u & 0x80000000u) ? 0xFFFFFFFFu : 0x80000000u);
}

// ---------------- 1. per-location inverse L2 norms over channels ----------
__global__ void norm_kernel(const float* __restrict__ cur,
                            const float* __restrict__ goal,
                            float* __restrict__ inv_cur,
                            float* __restrict__ inv_goal) {
    const int p = blockIdx.x * 256 + threadIdx.x;   // 0..1023
    const int b = blockIdx.y;
    const float* pc = cur  + (size_t)b * CHAN * HW + p;
    const float* pg = goal + (size_t)b * CHAN * HW + p;
    float sc = 0.f, sg = 0.f;
    for (int c = 0; c < CHAN; ++c) {
        float vc = pc[c * HW];
        float vg = pg[c * HW];
        sc += vc * vc;
        sg += vg * vg;
    }
    inv_cur[b * HW + p]  = 1.0f / fmaxf(sqrtf(sc), 1e-12f);
    inv_goal[b * HW + p] = 1.0f / fmaxf(sqrtf(sg), 1e-12f);
}

// ---------------- 2a. expand: f32 [b][c][p] -> scaled split-f16 [b][p][K2] -
// Each value v (normalized, *2^12) is split v = hi + lo (hi=f16(v),
// lo=f16(v-hi), exact). Slot layout along K2 (4 slots per channel):
//   A (cur):  (hi, hi, lo, lo)
//   B (goal): (hi, lo, hi, lo)
// so a plain f16 dot over K2 gives hi*hi + hi*lo + lo*hi + lo*lo
// = (hi+lo)*(hi'+lo') exactly (each f16*f16 product is exact in f32).
__global__ __launch_bounds__(256)
void expand_kernel(const float* __restrict__ cur, const float* __restrict__ goal,
                   const float* __restrict__ inv_cur, const float* __restrict__ inv_goal,
                   _Float16* __restrict__ Aexp, _Float16* __restrict__ Bexp, int b0) {
    const int isB = blockIdx.z;
    const int bl  = blockIdx.y;          // local batch within group
    const int b   = b0 + bl;             // global batch
    const int p0  = blockIdx.x * 64;
    const float* in  = isB ? goal : cur;
    const float* inv = isB ? inv_goal : inv_cur;
    _Float16* outb = (isB ? Bexp : Aexp) + (size_t)bl * HW * K2;

    __shared__ float inv_s[64];
    __shared__ unsigned long long stage[64][97];  // 776B padded rows (~48.5 KB)

    const int tid = threadIdx.x;
    if (tid < 64) inv_s[tid] = inv[b * HW + p0 + tid] * 4096.0f;  // fold 2^12 scale
    __syncthreads();

    const int p  = tid & 63;
    const int cO = tid >> 6;
    const float* src = in + (size_t)b * CHAN * HW + p0 + p;
    const float sc = inv_s[p];

    for (int ci = 0; ci < CHAN; ci += 96) {
#pragma unroll
        for (int i = 0; i < 24; ++i) {
            int c = ci + cO + i * 4;
            float v = src[(size_t)c * HW] * sc;
            _Float16 hi = (_Float16)v;
            _Float16 lo = (_Float16)(v - (float)hi);
            unsigned long long h = __builtin_bit_cast(unsigned short, hi);
            unsigned long long l = __builtin_bit_cast(unsigned short, lo);
            unsigned long long u = isB ? (h | (l << 16) | (h << 32) | (l << 48))
                                       : (h | (h << 16) | (l << 32) | (l << 48));
            stage[p][c - ci] = u;
        }
        __syncthreads();
        // coalesced write-out: 64 rows x 96 8B-units
#pragma unroll
        for (int i = 0; i < 24; ++i) {
            int idx = i * 256 + tid;
            int pp = idx / 96, u = idx % 96;
            *((unsigned long long*)(outb + (size_t)(p0 + pp) * K2) + (ci + u)) =
                stage[pp][u];
        }
        __syncthreads();
    }
}

// ---------------- 2b. MFMA GEMM: score = Aexp * Bexp^T (K2 contraction) ----
// 128x128 tile, BK=64 (f16), 4 waves of 64x64, 16x16x32 f16 MFMA.
// LDS tiles staged via global_load_lds width-16 with pre-swizzled global
// source so fragments read conflict-free: chunk c' = c ^ (m&7).
__global__ __launch_bounds__(256)
void gemm_mfma(const _Float16* __restrict__ Aexp, const _Float16* __restrict__ Bexp,
               float* __restrict__ score, int b0) {
    const int bl = blockIdx.z;
    const int m0 = blockIdx.x * 128;
    const int n0 = blockIdx.y * 128;
    __shared__ __align__(16) _Float16 Atile[128 * 64];  // 16 KB
    __shared__ __align__(16) _Float16 Btile[128 * 64];  // 16 KB
    const int tid = threadIdx.x;
    const int w  = tid >> 6, l = tid & 63;
    const int wr = w >> 1, wc = w & 1;
    const int lr = l & 15, lk = l >> 4;

    const _Float16* Ab = Aexp + ((size_t)bl * HW + m0) * K2;
    const _Float16* Bb = Bexp + ((size_t)bl * HW + n0) * K2;

    f32x4 acc[4][4] = {};

    for (int k0 = 0; k0 < K2; k0 += 64) {
        __syncthreads();
#pragma unroll
        for (int r = 0; r < 4; ++r) {
            int q  = (r * 4 + w) * 64 + l;       // 16B chunk id, 0..1023
            int m  = q >> 3;                     // tile row
            int cc = (q & 7) ^ (m & 7);          // source chunk (pre-swizzle)
            int ldsoff = (r * 4 + w) * 512;      // f16 elements; lane adds l*16B
            __builtin_amdgcn_global_load_lds(
                (const __attribute__((address_space(1))) unsigned int*)(Ab + (size_t)m * K2 + k0 + cc * 8),
                (__attribute__((address_space(3))) unsigned int*)(Atile + ldsoff), 16, 0, 0);
            __builtin_amdgcn_global_load_lds(
                (const __attribute__((address_space(1))) unsigned int*)(Bb + (size_t)m * K2 + k0 + cc * 8),
                (__attribute__((address_space(3))) unsigned int*)(Btile + ldsoff), 16, 0, 0);
        }
        __syncthreads();
#pragma unroll
        for (int kc = 0; kc < 2; ++kc) {
            f16x8 af[4], bf[4];
#pragma unroll
            for (int mi = 0; mi < 4; ++mi) {
                int m  = wr * 64 + mi * 16 + lr;
                int ch = (kc * 4 + lk) ^ (m & 7);
                af[mi] = *(const f16x8*)(Atile + m * 64 + ch * 8);
            }
#pragma unroll
            for (int ni = 0; ni < 4; ++ni) {
                int n  = wc * 64 + ni * 16 + lr;
                int ch = (kc * 4 + lk) ^ (n & 7);
                bf[ni] = *(const f16x8*)(Btile + n * 64 + ch * 8);
            }
#pragma unroll
            for (int mi = 0; mi < 4; ++mi)
#pragma unroll
                for (int ni = 0; ni < 4; ++ni)
                    acc[mi][ni] = __builtin_amdgcn_mfma_f32_16x16x32_f16(
                        af[mi], bf[ni], acc[mi][ni], 0, 0, 0);
        }
    }

    // epilogue: C/D layout col=lane&15, row=(lane>>4)*4+reg; undo 2^24 scale
    float* out = score + (size_t)(b0 + bl) * SM_PB;
#pragma unroll
    for (int mi = 0; mi < 4; ++mi) {
        int row0 = m0 + wr * 64 + mi * 16 + lk * 4;
#pragma unroll
        for (int ni = 0; ni < 4; ++ni) {
            int col = n0 + wc * 64 + ni * 16 + lr;
#pragma unroll
            for (int r = 0; r < 4; ++r)
                out[(size_t)(row0 + r) * HW + col] = acc[mi][ni][r] * 0x1p-24f;
        }
    }
}

// ---------------- 3. per-batch histogram of key top-12 bits ---------------
__global__ void hist_kernel(const float* __restrict__ score,
                            unsigned* __restrict__ ghist) {
    const int slice = blockIdx.x;   // 0..15
    const int b     = blockIdx.y;
    const int tid   = threadIdx.x;
    __shared__ unsigned hs[NBUCKET];
    for (int i = tid; i < NBUCKET; i += 256) hs[i] = 0;
    __syncthreads();
    const float4* base = (const float4*)(score + (size_t)b * SM_PB + slice * 65536);
    for (int it = 0; it < 64; ++it) {
        float4 v = base[it * 256 + tid];
        atomicAdd(&hs[mono_key(v.x) >> 20], 1u);
        atomicAdd(&hs[mono_key(v.y) >> 20], 1u);
        atomicAdd(&hs[mono_key(v.z) >> 20], 1u);
        atomicAdd(&hs[mono_key(v.w) >> 20], 1u);
    }
    __syncthreads();
    for (int i = tid; i < NBUCKET; i += 256)
        if (hs[i]) atomicAdd(&ghist[b * NBUCKET + i], hs[i]);
}

// ---------------- 4. find threshold bucket per batch ----------------------
__global__ void thresh_kernel(const unsigned* __restrict__ ghist,
                              unsigned* __restrict__ tbuf) {
    const int b = blockIdx.x;
    const int tid = threadIdx.x;
    __shared__ unsigned partial[256];
    unsigned s = 0;
    for (int j = 0; j < 16; ++j) s += ghist[b * NBUCKET + tid * 16 + j];
    partial[tid] = s;
    __syncthreads();
    if (tid == 0) {
        unsigned cum = 0;
        int T = 0;
        for (int t = 255; t >= 0; --t) {
            if (cum + partial[t] >= KTOP) {
                for (int k = t * 16 + 15; k >= t * 16; --k) {
                    cum += ghist[b * NBUCKET + k];
                    if (cum >= KTOP) { T = k; break; }
                }
                break;
            }
            cum += partial[t];
        }
        tbuf[b] = (unsigned)T;
    }
}

// ---------------- 5. collect candidates (bucket >= T) ---------------------
__global__ void collect_kernel(const float* __restrict__ score,
                               const unsigned* __restrict__ tbuf,
                               unsigned* __restrict__ cnt,
                               unsigned long long* __restrict__ cand) {
    const int slice = blockIdx.x;
    const int b     = blockIdx.y;
    const int tid   = threadIdx.x;
    const unsigned T = tbuf[b];
    const float4* base = (const float4*)(score + (size_t)b * SM_PB + slice * 65536);
    for (int it = 0; it < 64; ++it) {
        int e0 = slice * 65536 + (it * 256 + tid) * 4;
        float4 v = base[it * 256 + tid];
        float vals[4] = {v.x, v.y, v.z, v.w};
#pragma unroll
        for (int c = 0; c < 4; ++c) {
            unsigned key = mono_key(vals[c]);
            if ((key >> 20) >= T) {
                unsigned pos = atomicAdd(&cnt[b], 1u);
                if (pos < CAND_CAP)
                    cand[(size_t)b * CAND_CAP + pos] =
                        ((unsigned long long)key << 32) |
                        (unsigned long long)(0xFFFFFFFFu - (unsigned)(e0 + c));
            }
        }
    }
}

// ---------------- 6. select top-K, sort by index, build feats -------------
__global__ __launch_bounds__(1024)
void select_kernel(const unsigned long long* __restrict__ cand,
                   const unsigned* __restrict__ cnt,
                   const float* __restrict__ score,
                   float* __restrict__ feats) {
    const int b = blockIdx.x;
    const int tid = threadIdx.x;
    __shared__ unsigned long long arr[CAND_CAP];
    __shared__ unsigned idxs[KTOP];
    unsigned n = cnt[b];
    if (n > CAND_CAP) n = CAND_CAP;
    // adaptive sort length: next pow2 >= max(n, 1024)
    unsigned L = 1024;
    while (L < n) L <<= 1;
    for (int i = tid; i < (int)L; i += 1024)
        arr[i] = (i < (int)n) ? cand[(size_t)b * CAND_CAP + i] : 0ULL;
    __syncthreads();

    // bitonic sort descending on composite (key desc, idx asc)
    for (unsigned size = 2; size <= L; size <<= 1) {
        for (unsigned stride = size >> 1; stride > 0; stride >>= 1) {
            for (int i = tid; i < (int)L; i += 1024) {
                int j = i ^ (int)stride;
                if (j > i) {
                    unsigned long long a = arr[i], c = arr[j];
                    bool desc = ((i & size) == 0);
                    if (desc ? (a < c) : (a > c)) { arr[i] = c; arr[j] = a; }
                }
            }
            __syncthreads();
        }
    }

    // first K entries are the top-K; recover indices
    unsigned myidx = 0xFFFFFFFFu - (unsigned)(arr[tid] & 0xFFFFFFFFu);
    __syncthreads();
    idxs[tid] = myidx;
    __syncthreads();

    // bitonic sort ascending on index
    for (unsigned size = 2; size <= KTOP; size <<= 1) {
        for (unsigned stride = size >> 1; stride > 0; stride >>= 1) {
            int i = tid;
            int j = i ^ (int)stride;
            if (j > i && i < KTOP) {
                unsigned a = idxs[i], c = idxs[j];
                bool asc = ((i & size) == 0);
                if (asc ? (a > c) : (a < c)) { idxs[i] = c; idxs[j] = a; }
            }
            __syncthreads();
        }
    }

    unsigned idx = idxs[tid];
    float val = score[(size_t)b * SM_PB + idx];
    float* f = feats + (size_t)b * (KTOP * 3) + tid * 3;
    f[0] = (float)(idx >> 10);
    f[1] = (float)(idx & 1023);
    f[2] = val;
}

__device__ __forceinline__ float silu(float x) {
    return x / (1.0f + expf(-x));
}

// ---------------- 7. MLP layer 1: 3072 -> 1024 ----------------------------
__global__ void mlp1_kernel(const float* __restrict__ feats,
                            const float* __restrict__ W1,
                            const float* __restrict__ b1,
                            float* __restrict__ h1) {
    __shared__ float fs[3072];
    const int b = blockIdx.y, chunk = blockIdx.x, tid = threadIdx.x;
    for (int i = tid; i < 3072; i += 256) fs[i] = feats[(size_t)b * 3072 + i];
    __syncthreads();
    const int o = chunk * 256 + tid;
    float acc = b1[o];
    for (int k = 0; k < 3072; ++k) acc += fs[k] * W1[(size_t)k * 1024 + o];
    h1[(size_t)b * 1024 + o] = silu(acc);
}

// ---------------- 8. MLP layer 2: 1024 -> 256 -----------------------------
__global__ void mlp2_kernel(const float* __restrict__ h1,
                            const float* __restrict__ W2,
                            const float* __restrict__ b2,
                            float* __restrict__ h2) {
    __shared__ float hs[1024];
    const int b = blockIdx.x, tid = threadIdx.x;
    for (int i = tid; i < 1024; i += 256) hs[i] = h1[(size_t)b * 1024 + i];
    __syncthreads();
    float acc = b2[tid];
    for (int k = 0; k < 1024; ++k) acc += hs[k] * W2[(size_t)k * 256 + tid];
    h2[(size_t)b * 256 + tid] = silu(acc);
}

// ---------------- 9. MLP tail: 256->64->16->heads -------------------------
__global__ void tail_kernel(const float* __restrict__ h2,
                            const float* __restrict__ W3, const float* __restrict__ b3,
                            const float* __restrict__ W4, const float* __restrict__ b4,
                            const float* __restrict__ Wx, const float* __restrict__ bx,
                            const float* __restrict__ Wy, const float* __restrict__ by,
                            const float* __restrict__ Wr, const float* __restrict__ br,
                            float* __restrict__ action) {
    const int b = blockIdx.x, t = threadIdx.x;  // 64 threads
    __shared__ float h2s[256];
    __shared__ float h3s[64];
    __shared__ float h4s[16];
    for (int i = t; i < 256; i += 64) h2s[i] = h2[(size_t)b * 256 + i];
    __syncthreads();
    {
        float acc = b3[t];
        for (int k = 0; k < 256; ++k) acc += h2s[k] * W3[k * 64 + t];
        h3s[t] = silu(acc);
    }
    __syncthreads();
    if (t < 16) {
        float acc = b4[t];
        for (int k = 0; k < 64; ++k) acc += h3s[k] * W4[k * 16 + t];
        h4s[t] = silu(acc);
    }
    __syncthreads();
    if (t < 9) {
        int head = t / 3, j = t % 3;
        const float* Wh = (head == 0) ? Wx : (head == 1) ? Wy : Wr;
        const float* bh = (head == 0) ? bx : (head == 1) ? by : br;
        float acc = bh[j];
        for (int k = 0; k < 16; ++k) acc += h4s[k] * Wh[k * 3 + j];
        action[b * 9 + t] = acc;
    }
}

extern "C" void kernel_launch(void* const* d_in, const int* in_sizes, int n_in,
                              void* d_out, int out_size, void* d_ws, size_t ws_size,
                              hipStream_t stream) {
    const float* cur  = (const float*)d_in[0];
    const float* goal = (const float*)d_in[1];
    const float* W1 = (const float*)d_in[2];
    const float* b1 = (const float*)d_in[3];
    const float* W2 = (const float*)d_in[4];
    const float* b2 = (const float*)d_in[5];
    const float* W3 = (const float*)d_in[6];
    const float* b3 = (const float*)d_in[7];
    const float* W4 = (const float*)d_in[8];
    const float* b4 = (const float*)d_in[9];
    const float* Wx = (const float*)d_in[10];
    const float* bx = (const float*)d_in[11];
    const float* Wy = (const float*)d_in[12];
    const float* by = (const float*)d_in[13];
    const float* Wr = (const float*)d_in[14];
    const float* br = (const float*)d_in[15];

    float* out = (float*)d_out;
    float* score = out + OUT_OFF;
    char* ws = (char*)d_ws;

    float* inv_cur  = (float*)(ws + WS_INV_CUR);
    float* inv_goal = (float*)(ws + WS_INV_GOAL);
    unsigned* ghist = (unsigned*)(ws + WS_HIST);
    unsigned* cnt   = (unsigned*)(ws + WS_CNT);
    unsigned* tbuf  = (unsigned*)(ws + WS_TBUF);
    unsigned long long* cand = (unsigned long long*)(ws + WS_CAND);
    float* feats = (float*)(ws + WS_FEATS);
    float* h1    = (float*)(ws + WS_H1);
    float* h2    = (float*)(ws + WS_H2);

    // size the expansion group from available workspace (6.29 MB / batch)
    size_t avail = (ws_size > (size_t)WS_EXP) ? ws_size - (size_t)WS_EXP : 0;
    int g = (int)(avail / EXP_PB);
    if (g > BATCH) g = BATCH;
    if (g < 1) g = 1;
    _Float16* Aexp = (_Float16*)(ws + WS_EXP);
    _Float16* Bexp = Aexp + (size_t)g * HW * K2;

    // zero histogram + counters (ws is poisoned 0xAA before each call)
    hipMemsetAsync(ws + WS_HIST, 0, (size_t)BATCH * NBUCKET * 4 + 256, stream);

    norm_kernel<<<dim3(4, BATCH), 256, 0, stream>>>(cur, goal, inv_cur, inv_goal);

    for (int b0 = 0; b0 < BATCH; b0 += g) {
        int gb = (BATCH - b0 < g) ? (BATCH - b0) : g;
        expand_kernel<<<dim3(16, gb, 2), 256, 0, stream>>>(
            cur, goal, inv_cur, inv_goal, Aexp, Bexp, b0);
        gemm_mfma<<<dim3(8, 8, gb), 256, 0, stream>>>(Aexp, Bexp, score, b0);
    }

    hist_kernel<<<dim3(16, BATCH), 256, 0, stream>>>(score, ghist);
    thresh_kernel<<<dim3(BATCH), 256, 0, stream>>>(ghist, tbuf);
    collect_kernel<<<dim3(16, BATCH), 256, 0, stream>>>(score, tbuf, cnt, cand);
    select_kernel<<<dim3(BATCH), 1024, 0, stream>>>(cand, cnt, score, feats);
    mlp1_kernel<<<dim3(4, BATCH), 256, 0, stream>>>(feats, W1, b1, h1);
    mlp2_kernel<<<dim3(BATCH), 256, 0, stream>>>(h1, W2, b2, h2);
    tail_kernel<<<dim3(BATCH), 64, 0, stream>>>(h2, W3, b3, W4, b4,
                                                Wx, bx, Wy, by, Wr, br, out);
}

// Round 2
// 1462.406 us; speedup vs baseline: 1.2053x; 1.0948x over previous
//
#include <hip/hip_runtime.h>

// Problem constants
#define BATCH   64
#define CHAN    384
#define HW      1024
#define SM_PB   (HW * HW)          // score elements per batch = 1048576
#define OUT_OFF 576                // action floats before score matrix
#define KTOP    1024
#define NBUCKET 4096
#define CAND_CAP 8192
#define K2      1152               // expanded K: 3 f16 slots per channel

// Workspace byte offsets
#define WS_HIST      524288                 // 64*4096*4 = 1048576
#define WS_CNT       1572864                // 64*4 (padded to 256)
#define WS_TBUF      1573120                // 64*4 (padded to 256)
#define WS_CAND      1573376                // 64*8192*8 = 4194304
#define WS_FEATS     5767680                // 64*3072*4 = 786432
#define WS_H1        6554112                // 64*1024*4 = 262144
#define WS_H2        6816256                // 64*256*4  = 65536
#define WS_EXP       6881792                // expanded f16 buffers start here
#define EXP_PB       4718592ULL             // bytes/batch: 2 ops * 1024 * 1152 * 2B

using f16x8 = __attribute__((ext_vector_type(8))) _Float16;
using f32x4 = __attribute__((ext_vector_type(4))) float;

__device__ __forceinline__ unsigned mono_key(float f) {
    unsigned u = __float_as_uint(f);
    return u ^ ((u & 0x80000000u) ? 0xFFFFFFFFu : 0x80000000u);
}

// ---------------- 1. fused norm + expand ----------------------------------
// f32 [b][c][p] -> scaled split-f16 [b][p][K2], K2 region-blocked:
//   k' = r*384 + c;  A slots per region: (hi, lo, hi);  B: (hi, hi, lo)
// dot over K2 = hi*hi' + lo*hi' + hi*lo' = v*v' - lo*lo'  (|lo*lo'| <= 2^-22 rel)
// Values scaled by 2^12 (norm folded); each f16 product exact in f32.
__global__ __launch_bounds__(256)
void expand_kernel(const float* __restrict__ cur, const float* __restrict__ goal,
                   _Float16* __restrict__ Aexp, _Float16* __restrict__ Bexp, int b0) {
    const int isB = blockIdx.z;
    const int bl  = blockIdx.y;          // local batch within group
    const int b   = b0 + bl;             // global batch
    const int p0  = blockIdx.x * 32;
    const float* in = isB ? goal : cur;
    _Float16* outb = (isB ? Bexp : Aexp) + (size_t)bl * HW * K2;

    __shared__ float fbuf[32][385];      // +1 pad: conflict-free phase-1 writes
    __shared__ float ss[8][32];
    __shared__ float inv_s[32];

    const int tid = threadIdx.x;
    const int p  = tid & 31;
    const int cO = tid >> 5;             // 0..7
    const float* src = in + (size_t)b * CHAN * HW + p0 + p;
    float s = 0.f;
    for (int c = cO; c < CHAN; c += 8) {
        float v = src[(size_t)c * HW];
        fbuf[p][c] = v;
        s += v * v;
    }
    ss[cO][p] = s;
    __syncthreads();
    if (tid < 32) {
        float t = 0.f;
#pragma unroll
        for (int j = 0; j < 8; ++j) t += ss[j][tid];
        inv_s[tid] = 4096.0f / fmaxf(sqrtf(t), 1e-12f);
    }
    __syncthreads();

    // writeout: 3 regions x 32 p x 96 ulongs (4 f16 each) = 9216 ulongs
#pragma unroll
    for (int i = 0; i < 36; ++i) {
        int idx = i * 256 + tid;
        int r   = idx / 3072;
        int rem = idx - r * 3072;
        int pp  = rem / 96;
        int u   = rem - pp * 96;
        bool need_lo = isB ? (r == 2) : (r == 1);
        float sc = inv_s[pp];
        unsigned long long w = 0;
#pragma unroll
        for (int j = 0; j < 4; ++j) {
            float v = fbuf[pp][u * 4 + j] * sc;
            _Float16 hi = (_Float16)v;
            _Float16 e  = need_lo ? (_Float16)(v - (float)hi) : hi;
            w |= (unsigned long long)__builtin_bit_cast(unsigned short, e) << (16 * j);
        }
        *((unsigned long long*)(outb + (size_t)(p0 + pp) * K2 + r * 384) + u) = w;
    }
}

// ---------------- 2. MFMA GEMM: score = Aexp * Bexp^T (K2 contraction) ----
// 128x128 tile, BK=64 f16, 4 waves, 16x16x32 MFMA, global_load_lds w=16
// with pre-swizzled global source (chunk c' = c ^ (m&7)) -> conflict-free
// ds_read_b128. Flat grid with XCD-aware mapping: wgid % 8 == batch % 8 so
// each batch's 64 tiles share one XCD's L2 (panels ~4.7 MB vs 4 MB L2).
__global__ __launch_bounds__(256)
void gemm_mfma(const _Float16* __restrict__ Aexp, const _Float16* __restrict__ Bexp,
               float* __restrict__ score, int b0, int gb) {
    int wg = blockIdx.x;
    int b, t;
    if ((gb & 7) == 0) {
        int lowb = wg & 7;
        int q = wg >> 3;
        t = q & 63;
        b = (q >> 6) * 8 + lowb;
    } else {
        b = wg >> 6;
        t = wg & 63;
    }
    const int m0 = (t & 7) * 128;
    const int n0 = (t >> 3) * 128;
    __shared__ __align__(16) _Float16 Atile[128 * 64];  // 16 KB
    __shared__ __align__(16) _Float16 Btile[128 * 64];  // 16 KB
    const int tid = threadIdx.x;
    const int w  = tid >> 6, l = tid & 63;
    const int wr = w >> 1, wc = w & 1;
    const int lr = l & 15, lk = l >> 4;

    const _Float16* Ab = Aexp + ((size_t)b * HW + m0) * K2;
    const _Float16* Bb = Bexp + ((size_t)b * HW + n0) * K2;

    f32x4 acc[4][4] = {};

    for (int k0 = 0; k0 < K2; k0 += 64) {
        __syncthreads();
#pragma unroll
        for (int r = 0; r < 4; ++r) {
            int q  = (r * 4 + w) * 64 + l;       // 16B chunk id, 0..1023
            int m  = q >> 3;                     // tile row
            int cc = (q & 7) ^ (m & 7);          // source chunk (pre-swizzle)
            int ldsoff = (r * 4 + w) * 512;      // f16 elements; lane adds l*16B
            __builtin_amdgcn_global_load_lds(
                (const __attribute__((address_space(1))) unsigned int*)(Ab + (size_t)m * K2 + k0 + cc * 8),
                (__attribute__((address_space(3))) unsigned int*)(Atile + ldsoff), 16, 0, 0);
            __builtin_amdgcn_global_load_lds(
                (const __attribute__((address_space(1))) unsigned int*)(Bb + (size_t)m * K2 + k0 + cc * 8),
                (__attribute__((address_space(3))) unsigned int*)(Btile + ldsoff), 16, 0, 0);
        }
        __syncthreads();
#pragma unroll
        for (int kc = 0; kc < 2; ++kc) {
            f16x8 af[4], bf[4];
#pragma unroll
            for (int mi = 0; mi < 4; ++mi) {
                int m  = wr * 64 + mi * 16 + lr;
                int ch = (kc * 4 + lk) ^ (m & 7);
                af[mi] = *(const f16x8*)(Atile + m * 64 + ch * 8);
            }
#pragma unroll
            for (int ni = 0; ni < 4; ++ni) {
                int n  = wc * 64 + ni * 16 + lr;
                int ch = (kc * 4 + lk) ^ (n & 7);
                bf[ni] = *(const f16x8*)(Btile + n * 64 + ch * 8);
            }
#pragma unroll
            for (int mi = 0; mi < 4; ++mi)
#pragma unroll
                for (int ni = 0; ni < 4; ++ni)
                    acc[mi][ni] = __builtin_amdgcn_mfma_f32_16x16x32_f16(
                        af[mi], bf[ni], acc[mi][ni], 0, 0, 0);
        }
    }

    // epilogue: C/D layout col=lane&15, row=(lane>>4)*4+reg; undo 2^24 scale
    float* out = score + (size_t)(b0 + b) * SM_PB;
#pragma unroll
    for (int mi = 0; mi < 4; ++mi) {
        int row0 = m0 + wr * 64 + mi * 16 + lk * 4;
#pragma unroll
        for (int ni = 0; ni < 4; ++ni) {
            int col = n0 + wc * 64 + ni * 16 + lr;
#pragma unroll
            for (int r = 0; r < 4; ++r)
                out[(size_t)(row0 + r) * HW + col] = acc[mi][ni][r] * 0x1p-24f;
        }
    }
}

// ---------------- 3. per-batch histogram of key top-12 bits ---------------
// Two LDS copies split by lane parity to halve same-address atomic serialization.
__global__ void hist_kernel(const float* __restrict__ score,
                            unsigned* __restrict__ ghist) {
    const int slice = blockIdx.x;   // 0..15
    const int b     = blockIdx.y;
    const int tid   = threadIdx.x;
    __shared__ unsigned hs[2][NBUCKET];   // 32 KB
    for (int i = tid; i < NBUCKET; i += 256) { hs[0][i] = 0; hs[1][i] = 0; }
    __syncthreads();
    const int par = tid & 1;
    const float4* base = (const float4*)(score + (size_t)b * SM_PB + slice * 65536);
    for (int it = 0; it < 64; ++it) {
        float4 v = base[it * 256 + tid];
        atomicAdd(&hs[par    ][mono_key(v.x) >> 20], 1u);
        atomicAdd(&hs[par ^ 1][mono_key(v.y) >> 20], 1u);
        atomicAdd(&hs[par    ][mono_key(v.z) >> 20], 1u);
        atomicAdd(&hs[par ^ 1][mono_key(v.w) >> 20], 1u);
    }
    __syncthreads();
    for (int i = tid; i < NBUCKET; i += 256) {
        unsigned u = hs[0][i] + hs[1][i];
        if (u) atomicAdd(&ghist[b * NBUCKET + i], u);
    }
}

// ---------------- 4. find threshold bucket per batch (LDS-resident) -------
__global__ void thresh_kernel(const unsigned* __restrict__ ghist,
                              unsigned* __restrict__ tbuf) {
    const int b = blockIdx.x;
    const int tid = threadIdx.x;
    __shared__ unsigned hsl[NBUCKET];
    __shared__ unsigned partial[256];
    unsigned s = 0;
    for (int j = 0; j < 16; ++j) {
        unsigned u = ghist[b * NBUCKET + tid * 16 + j];
        hsl[tid * 16 + j] = u;
        s += u;
    }
    partial[tid] = s;
    __syncthreads();
    if (tid == 0) {
        unsigned cum = 0;
        int T = 0;
        for (int t = 255; t >= 0; --t) {
            if (cum + partial[t] >= KTOP) {
                for (int k = t * 16 + 15; k >= t * 16; --k) {
                    cum += hsl[k];
                    if (cum >= KTOP) { T = k; break; }
                }
                break;
            }
            cum += partial[t];
        }
        tbuf[b] = (unsigned)T;
    }
}

// ---------------- 5. collect candidates (bucket >= T) ---------------------
__global__ void collect_kernel(const float* __restrict__ score,
                               const unsigned* __restrict__ tbuf,
                               unsigned* __restrict__ cnt,
                               unsigned long long* __restrict__ cand) {
    const int slice = blockIdx.x;
    const int b     = blockIdx.y;
    const int tid   = threadIdx.x;
    const unsigned T = tbuf[b];
    const float4* base = (const float4*)(score + (size_t)b * SM_PB + slice * 65536);
    for (int it = 0; it < 64; ++it) {
        int e0 = slice * 65536 + (it * 256 + tid) * 4;
        float4 v = base[it * 256 + tid];
        float vals[4] = {v.x, v.y, v.z, v.w};
#pragma unroll
        for (int c = 0; c < 4; ++c) {
            unsigned key = mono_key(vals[c]);
            if ((key >> 20) >= T) {
                unsigned pos = atomicAdd(&cnt[b], 1u);
                if (pos < CAND_CAP)
                    cand[(size_t)b * CAND_CAP + pos] =
                        ((unsigned long long)key << 32) |
                        (unsigned long long)(0xFFFFFFFFu - (unsigned)(e0 + c));
            }
        }
    }
}

// ---------------- 6. select top-K, sort by index, build feats -------------
__global__ __launch_bounds__(1024)
void select_kernel(const unsigned long long* __restrict__ cand,
                   const unsigned* __restrict__ cnt,
                   const float* __restrict__ score,
                   float* __restrict__ feats) {
    const int b = blockIdx.x;
    const int tid = threadIdx.x;
    __shared__ unsigned long long arr[CAND_CAP];
    __shared__ unsigned idxs[KTOP];
    unsigned n = cnt[b];
    if (n > CAND_CAP) n = CAND_CAP;
    // adaptive sort length: next pow2 >= max(n, 1024)
    unsigned L = 1024;
    while (L < n) L <<= 1;
    for (int i = tid; i < (int)L; i += 1024)
        arr[i] = (i < (int)n) ? cand[(size_t)b * CAND_CAP + i] : 0ULL;
    __syncthreads();

    // bitonic sort descending on composite (key desc, idx asc)
    for (unsigned size = 2; size <= L; size <<= 1) {
        for (unsigned stride = size >> 1; stride > 0; stride >>= 1) {
            for (int i = tid; i < (int)L; i += 1024) {
                int j = i ^ (int)stride;
                if (j > i) {
                    unsigned long long a = arr[i], c = arr[j];
                    bool desc = ((i & size) == 0);
                    if (desc ? (a < c) : (a > c)) { arr[i] = c; arr[j] = a; }
                }
            }
            __syncthreads();
        }
    }

    // first K entries are the top-K; recover indices
    unsigned myidx = 0xFFFFFFFFu - (unsigned)(arr[tid] & 0xFFFFFFFFu);
    __syncthreads();
    idxs[tid] = myidx;
    __syncthreads();

    // bitonic sort ascending on index
    for (unsigned size = 2; size <= KTOP; size <<= 1) {
        for (unsigned stride = size >> 1; stride > 0; stride >>= 1) {
            int i = tid;
            int j = i ^ (int)stride;
            if (j > i && i < KTOP) {
                unsigned a = idxs[i], c = idxs[j];
                bool asc = ((i & size) == 0);
                if (asc ? (a > c) : (a < c)) { idxs[i] = c; idxs[j] = a; }
            }
            __syncthreads();
        }
    }

    unsigned idx = idxs[tid];
    float val = score[(size_t)b * SM_PB + idx];
    float* f = feats + (size_t)b * (KTOP * 3) + tid * 3;
    f[0] = (float)(idx >> 10);
    f[1] = (float)(idx & 1023);
    f[2] = val;
}

__device__ __forceinline__ float silu(float x) {
    return x / (1.0f + expf(-x));
}

// ---------------- 7. MLP layer 1: 3072 -> 1024 ----------------------------
__global__ void mlp1_kernel(const float* __restrict__ feats,
                            const float* __restrict__ W1,
                            const float* __restrict__ b1,
                            float* __restrict__ h1) {
    __shared__ float fs[3072];
    const int b = blockIdx.y, chunk = blockIdx.x, tid = threadIdx.x;
    for (int i = tid; i < 3072; i += 256) fs[i] = feats[(size_t)b * 3072 + i];
    __syncthreads();
    const int o = chunk * 256 + tid;
    float acc = b1[o];
    for (int k = 0; k < 3072; ++k) acc += fs[k] * W1[(size_t)k * 1024 + o];
    h1[(size_t)b * 1024 + o] = silu(acc);
}

// ---------------- 8. MLP layer 2: 1024 -> 256 -----------------------------
__global__ void mlp2_kernel(const float* __restrict__ h1,
                            const float* __restrict__ W2,
                            const float* __restrict__ b2,
                            float* __restrict__ h2) {
    __shared__ float hs[1024];
    const int b = blockIdx.x, tid = threadIdx.x;
    for (int i = tid; i < 1024; i += 256) hs[i] = h1[(size_t)b * 1024 + i];
    __syncthreads();
    float acc = b2[tid];
    for (int k = 0; k < 1024; ++k) acc += hs[k] * W2[(size_t)k * 256 + tid];
    h2[(size_t)b * 256 + tid] = silu(acc);
}

// ---------------- 9. MLP tail: 256->64->16->heads -------------------------
__global__ void tail_kernel(const float* __restrict__ h2,
                            const float* __restrict__ W3, const float* __restrict__ b3,
                            const float* __restrict__ W4, const float* __restrict__ b4,
                            const float* __restrict__ Wx, const float* __restrict__ bx,
                            const float* __restrict__ Wy, const float* __restrict__ by,
                            const float* __restrict__ Wr, const float* __restrict__ br,
                            float* __restrict__ action) {
    const int b = blockIdx.x, t = threadIdx.x;  // 64 threads
    __shared__ float h2s[256];
    __shared__ float h3s[64];
    __shared__ float h4s[16];
    for (int i = t; i < 256; i += 64) h2s[i] = h2[(size_t)b * 256 + i];
    __syncthreads();
    {
        float acc = b3[t];
        for (int k = 0; k < 256; ++k) acc += h2s[k] * W3[k * 64 + t];
        h3s[t] = silu(acc);
    }
    __syncthreads();
    if (t < 16) {
        float acc = b4[t];
        for (int k = 0; k < 64; ++k) acc += h3s[k] * W4[k * 16 + t];
        h4s[t] = silu(acc);
    }
    __syncthreads();
    if (t < 9) {
        int head = t / 3, j = t % 3;
        const float* Wh = (head == 0) ? Wx : (head == 1) ? Wy : Wr;
        const float* bh = (head == 0) ? bx : (head == 1) ? by : br;
        float acc = bh[j];
        for (int k = 0; k < 16; ++k) acc += h4s[k] * Wh[k * 3 + j];
        action[b * 9 + t] = acc;
    }
}

extern "C" void kernel_launch(void* const* d_in, const int* in_sizes, int n_in,
                              void* d_out, int out_size, void* d_ws, size_t ws_size,
                              hipStream_t stream) {
    const float* cur  = (const float*)d_in[0];
    const float* goal = (const float*)d_in[1];
    const float* W1 = (const float*)d_in[2];
    const float* b1 = (const float*)d_in[3];
    const float* W2 = (const float*)d_in[4];
    const float* b2 = (const float*)d_in[5];
    const float* W3 = (const float*)d_in[6];
    const float* b3 = (const float*)d_in[7];
    const float* W4 = (const float*)d_in[8];
    const float* b4 = (const float*)d_in[9];
    const float* Wx = (const float*)d_in[10];
    const float* bx = (const float*)d_in[11];
    const float* Wy = (const float*)d_in[12];
    const float* by = (const float*)d_in[13];
    const float* Wr = (const float*)d_in[14];
    const float* br = (const float*)d_in[15];

    float* out = (float*)d_out;
    float* score = out + OUT_OFF;
    char* ws = (char*)d_ws;

    unsigned* ghist = (unsigned*)(ws + WS_HIST);
    unsigned* cnt   = (unsigned*)(ws + WS_CNT);
    unsigned* tbuf  = (unsigned*)(ws + WS_TBUF);
    unsigned long long* cand = (unsigned long long*)(ws + WS_CAND);
    float* feats = (float*)(ws + WS_FEATS);
    float* h1    = (float*)(ws + WS_H1);
    float* h2    = (float*)(ws + WS_H2);

    // size the expansion group from available workspace (4.72 MB / batch);
    // keep g a multiple of 8 so the XCD swizzle stays bijective
    size_t avail = (ws_size > (size_t)WS_EXP) ? ws_size - (size_t)WS_EXP : 0;
    int g = (int)(avail / EXP_PB);
    if (g > BATCH) g = BATCH;
    if (g >= 8) g &= ~7;
    if (g < 1) g = 1;
    _Float16* Aexp = (_Float16*)(ws + WS_EXP);
    _Float16* Bexp = Aexp + (size_t)g * HW * K2;

    // zero histogram + counters (ws is poisoned 0xAA before each call)
    hipMemsetAsync(ws + WS_HIST, 0, (size_t)BATCH * NBUCKET * 4 + 256, stream);

    for (int b0 = 0; b0 < BATCH; b0 += g) {
        int gb = (BATCH - b0 < g) ? (BATCH - b0) : g;
        expand_kernel<<<dim3(32, gb, 2), 256, 0, stream>>>(
            cur, goal, Aexp, Bexp, b0);
        gemm_mfma<<<dim3(64 * gb), 256, 0, stream>>>(Aexp, Bexp, score, b0, gb);
    }

    hist_kernel<<<dim3(16, BATCH), 256, 0, stream>>>(score, ghist);
    thresh_kernel<<<dim3(BATCH), 256, 0, stream>>>(ghist, tbuf);
    collect_kernel<<<dim3(16, BATCH), 256, 0, stream>>>(score, tbuf, cnt, cand);
    select_kernel<<<dim3(BATCH), 1024, 0, stream>>>(cand, cnt, score, feats);
    mlp1_kernel<<<dim3(4, BATCH), 256, 0, stream>>>(feats, W1, b1, h1);
    mlp2_kernel<<<dim3(BATCH), 256, 0, stream>>>(h1, W2, b2, h2);
    tail_kernel<<<dim3(BATCH), 64, 0, stream>>>(h2, W3, b3, W4, b4,
                                                Wx, bx, Wy, by, Wr, br, out);
}